// Round 12
// baseline (272.866 us; speedup 1.0000x reference)
//
#include <hip/hip_runtime.h>
#include <hip/hip_bf16.h>

#define D_MODEL 1024
#define N_HEADS 16
#define DK 64
#define B_SZ 4
#define T_SEQ 2048
#define M_ROWS (B_SZ * T_SEQ)   // 8192
#define QK_SCALE_LOG2 0.18033688f   // 0.125 * log2(e), folded into W_qkv Q-rows

#define XN ((size_t)M_ROWS * D_MODEL)        // 8388608
#define WQ ((size_t)3 * D_MODEL * D_MODEL)   // 3145728
#define WP ((size_t)D_MODEL * D_MODEL)       // 1048576

typedef short bf16x8 __attribute__((ext_vector_type(8)));
typedef float f32x4  __attribute__((ext_vector_type(4)));

__device__ inline unsigned short f32_to_bf16(float f) {
    union { float f; unsigned int u; } v; v.f = f;
    unsigned int r = v.u + 0x7fff + ((v.u >> 16) & 1);   // RNE
    return (unsigned short)(r >> 16);
}
__device__ inline unsigned int pack_bf16x2(float a, float b) {
    __hip_bfloat162 t = __float22bfloat162_rn(make_float2(a, b));
    union { __hip_bfloat162 v; unsigned int u; } c; c.v = t;
    return c.u;   // low 16 = a
}

// ---------------------------------------------------------------------------
// R23 cast: x -> linear bf16; W planes -> FRAGMENT-MAJOR bf16:
//   Wf[(ntile*128 + k8)*128 + (n&127)][8], element (n,k) at frag (ntile,k>>3),
//   row n&127, slot k&7. A GEMM quad-group (16 lanes) then reads one 256B
//   contiguous fragment run directly from global (attn's vt pattern).
// Reads coalesced (32B/thread); writes are 16B at 2KB stride (one-time cost).
// ---------------------------------------------------------------------------
__global__ __launch_bounds__(256) void cast_all(
    const float* __restrict__ x, const float* __restrict__ W_qkv,
    const float* __restrict__ W_proj,
    unsigned short* __restrict__ xb, unsigned short* __restrict__ wqb,
    unsigned short* __restrict__ wpb)
{
    const size_t NX4 = XN / 4;
    const size_t NQ8 = WQ / 8;
    const size_t NP8 = WP / 8;
    const size_t total = NX4 + NQ8 + NP8;
    for (size_t idx = blockIdx.x * 256 + threadIdx.x; idx < total;
         idx += gridDim.x * 256) {
        if (idx < NX4) {
            const size_t off = idx * 4;
            float4 v = *(const float4*)(x + off);
            ushort4 h;
            h.x = f32_to_bf16(v.x); h.y = f32_to_bf16(v.y);
            h.z = f32_to_bf16(v.z); h.w = f32_to_bf16(v.w);
            *(ushort4*)(xb + off) = h;
        } else {
            const float* src; unsigned short* dst; size_t j; float sc = 1.0f;
            if (idx < NX4 + NQ8) {
                j = idx - NX4; src = W_qkv; dst = wqb;
                if ((j >> 7) < (size_t)D_MODEL) sc = QK_SCALE_LOG2;
            } else {
                j = idx - NX4 - NQ8; src = W_proj; dst = wpb;
            }
            const int n  = (int)(j >> 7);
            const int k8 = (int)(j & 127);
            const float* s = src + ((size_t)n << 10) + (k8 << 3);
            float4 v0 = *(const float4*)(s);
            float4 v1 = *(const float4*)(s + 4);
            union { unsigned short h[8]; uint4 u; } o;
            o.h[0] = f32_to_bf16(v0.x * sc); o.h[1] = f32_to_bf16(v0.y * sc);
            o.h[2] = f32_to_bf16(v0.z * sc); o.h[3] = f32_to_bf16(v0.w * sc);
            o.h[4] = f32_to_bf16(v1.x * sc); o.h[5] = f32_to_bf16(v1.y * sc);
            o.h[6] = f32_to_bf16(v1.z * sc); o.h[7] = f32_to_bf16(v1.w * sc);
            unsigned short* d =
                dst + ((((size_t)(n >> 7) * 128 + k8) * 128 + (n & 127)) << 3);
            *(uint4*)d = o.u;
        }
    }
}

// ---------------------------------------------------------------------------
// bf16 GEMM, R23: B operand read DIRECTLY from global in fragment-major
// layout (attn's vt pattern — 256B contiguous per quad-group), no sB.
//   * LDS halves to 32KB (A dbuf only) -> 3 blocks/CU (VGPR-capped).
//   * B register loads issue FIRST after the barrier (oldest in vmem FIFO),
//     A gload_lds prefetch after -> B waits never drain the A prefetch
//     (R14/R17 lesson).
//   * XCD mapping N-major-within-XCD: per-XCD B slice <=0.75MB stays
//     L2-resident (B is now latency-critical; A is prefetch-tolerant).
// One-barrier dbuf K-loop (R22) kept. FUSE_VT (R20) kept.
// ---------------------------------------------------------------------------
template <typename OutT, bool FUSE_VT>
__global__ __launch_bounds__(256, 3) void gemm_bf16_nt(
    const unsigned short* __restrict__ A, const unsigned short* __restrict__ Bf,
    OutT* __restrict__ C, unsigned short* __restrict__ vt,
    int M, int N, int K)
{
    __shared__ __align__(16) unsigned short sA[2][128 * 64];

    const int t    = threadIdx.x;
    const int wave = t >> 6;
    const int lane = t & 63;
    const int l15  = lane & 15;
    const int quad = lane >> 4;
    const int swz  = l15 & 7;

    // Bijective XCD swizzle, N-major within each XCD (B L2-resident).
    const int cpx = gridDim.x >> 3;
    const int wg  = (blockIdx.x & 7) * cpx + (blockIdx.x >> 3);
    const int nbm = M >> 7;
    const int n0  = (wg / nbm) * 128;
    const int m0  = (wg % nbm) * 128;

    // A staging: all 4 waves, 32 rows each, 4 gload_lds/thread per K-tile.
    const int rsub = lane >> 3;
    const int cg   = (lane & 7) ^ rsub;         // pre-swizzled source col-group
    const unsigned short* gbase =
        A + (size_t)(m0 + wave * 32 + rsub) * K + cg * 8;

    const int wr = (wave >> 1) * 64;
    const int wc = (wave & 1) * 64;
    // B fragment base: frag index (n0>>7)*128 + kt*8 + ch; row wc+f*16+l15.
    const unsigned short* bfb =
        Bf + (((size_t)(n0 >> 7) * 128) * 128 + wc + l15) * 8;

    f32x4 acc[4][4];
#pragma unroll
    for (int i = 0; i < 4; ++i)
#pragma unroll
        for (int j = 0; j < 4; ++j) acc[i][j] = (f32x4){0.f, 0.f, 0.f, 0.f};

    const int nk = K >> 6;
    // prologue: stage A K-tile 0 into buffer 0
#pragma unroll
    for (int i = 0; i < 4; ++i) {
        __builtin_amdgcn_global_load_lds(
            (const __attribute__((address_space(1))) unsigned int*)
                (gbase + (size_t)(i * 8) * K),
            (__attribute__((address_space(3))) unsigned int*)
                (&sA[0][wave * 2048 + i * 512]),
            16, 0, 0);
    }

    for (int kt = 0; kt < nk; ++kt) {
        __syncthreads();   // drains this tile's A loads (issued one iter ago)

        // B fragments FIRST (oldest in vmem queue).
        const unsigned short* bk = bfb + (size_t)(kt * 8 + quad) * 1024;
        bf16x8 b0[4], b1[4];
#pragma unroll
        for (int f = 0; f < 4; ++f) b0[f] = *(const bf16x8*)(bk + f * 128);
#pragma unroll
        for (int f = 0; f < 4; ++f) b1[f] = *(const bf16x8*)(bk + 4096 + f * 128);

        // A prefetch for next K-tile (drains at next barrier).
        if (kt + 1 < nk) {
            const int k0n = (kt + 1) << 6;
            const int nb  = (kt + 1) & 1;
#pragma unroll
            for (int i = 0; i < 4; ++i) {
                __builtin_amdgcn_global_load_lds(
                    (const __attribute__((address_space(1))) unsigned int*)
                        (gbase + k0n + (size_t)(i * 8) * K),
                    (__attribute__((address_space(3))) unsigned int*)
                        (&sA[nb][wave * 2048 + i * 512]),
                    16, 0, 0);
            }
        }

        const int cb = kt & 1;
#pragma unroll
        for (int kk = 0; kk < 2; ++kk) {
            bf16x8 a[4];
            const int ch = kk * 4 + quad;
            const int co = (ch ^ swz) * 8;
#pragma unroll
            for (int f = 0; f < 4; ++f)
                a[f] = *(const bf16x8*)&sA[cb][(wr + f * 16 + l15) * 64 + co];
            __builtin_amdgcn_s_setprio(1);
#pragma unroll
            for (int mi = 0; mi < 4; ++mi)
#pragma unroll
                for (int ni = 0; ni < 4; ++ni)
                    acc[mi][ni] = __builtin_amdgcn_mfma_f32_16x16x32_bf16(
                        a[mi], (kk ? b1 : b0)[ni], acc[mi][ni], 0, 0, 0);
            __builtin_amdgcn_s_setprio(0);
        }
    }

    if constexpr (FUSE_VT) {
        if (n0 >= 2 * D_MODEL) {
            // V tile: write attn-ready vt fragments only (no qkvb write).
            const int bb   = m0 >> 11;            // batch (2048 rows each)
            const int tile = (m0 & 2047) >> 7;    // kv tile within batch
            const int hA   = (n0 + wc - 2 * D_MODEL) >> 6;   // head of this wave
            unsigned short* vtile =
                vt + ((size_t)((bb * N_HEADS + hA) * (T_SEQ / 128) + tile))
                     * (16 * 64 * 8);
            const int chi = (wr >> 6) * 8;
#pragma unroll
            for (int cc = 0; cc < 2; ++cc) {
                const int c   = chi + cc * 4 + quad;
                const int mi0 = 2 * cc;
#pragma unroll
                for (int ni = 0; ni < 4; ++ni) {
                    const int d = ni * 16 + l15;
                    uint4 p;
                    p.x = pack_bf16x2(acc[mi0][ni][0],     acc[mi0][ni][1]);
                    p.y = pack_bf16x2(acc[mi0][ni][2],     acc[mi0][ni][3]);
                    p.z = pack_bf16x2(acc[mi0 + 1][ni][0], acc[mi0 + 1][ni][1]);
                    p.w = pack_bf16x2(acc[mi0 + 1][ni][2], acc[mi0 + 1][ni][3]);
                    *(uint4*)(vtile + (c * 64 + d) * 8) = p;
                }
            }
            return;
        }
    }

#pragma unroll
    for (int mi = 0; mi < 4; ++mi)
#pragma unroll
        for (int r = 0; r < 4; ++r) {
            OutT* crow =
                C + (size_t)(m0 + wr + mi * 16 + quad * 4 + r) * N + n0 + wc + l15;
#pragma unroll
            for (int ni = 0; ni < 4; ++ni) {
                if constexpr (sizeof(OutT) == 2)
                    crow[ni * 16] = (OutT)f32_to_bf16(acc[mi][ni][r]);
                else
                    crow[ni * 16] = (OutT)acc[mi][ni][r];
            }
        }
}

// ---------------------------------------------------------------------------
// MFMA flash attention. R16 structure (best measured) — setprio around MFMA
// clusters, V at point of use from fragment-major global layout, K double-
// buffered via global_load_lds. R14/R15/R17/R18 all regressed: no extra V
// register buffering, no bigger Q tile.
// ---------------------------------------------------------------------------
__global__ __launch_bounds__(256, 4) void attn_mfma(
    const unsigned short* __restrict__ qkvb,   // [B,T,3D] bf16 (Q pre-scaled)
    const unsigned short* __restrict__ vt,     // [bh][tile][16][64][8] bf16
    unsigned short* __restrict__ ob)           // [B,T,D] bf16
{
    __shared__ __align__(16) unsigned short Ksw[2][128 * 64];  // [kv][dk] swizzled

    const int t    = threadIdx.x;
    const int wave = t >> 6;
    const int lane = t & 63;
    const int l15  = t & 15;
    const int quad = lane >> 4;
    const int swz  = l15 & 7;

    const int b  = blockIdx.z;
    const int h  = blockIdx.y;
    const int q0 = blockIdx.x * 128;

    // Q fragments (loop-invariant): 2 q-subtiles x 2 dk-chunks
    bf16x8 qa[2][2];
#pragma unroll
    for (int qs = 0; qs < 2; ++qs) {
        const unsigned short* qrow =
            qkvb + ((size_t)(b * T_SEQ) + q0 + wave * 32 + qs * 16 + l15)
                   * (3 * D_MODEL) + h * DK;
        qa[qs][0] = *(const bf16x8*)(qrow + quad * 8);
        qa[qs][1] = *(const bf16x8*)(qrow + 32 + quad * 8);
    }

    f32x4 O[2][4], Lacc[2];
#pragma unroll
    for (int qs = 0; qs < 2; ++qs) {
        Lacc[qs] = (f32x4){0.f, 0.f, 0.f, 0.f};
#pragma unroll
        for (int nd = 0; nd < 4; ++nd) O[qs][nd] = (f32x4){0.f, 0.f, 0.f, 0.f};
    }

    const short one_bf = (short)0x3F80;
    const bf16x8 ones8 = {one_bf, one_bf, one_bf, one_bf,
                          one_bf, one_bf, one_bf, one_bf};

    const unsigned short* kbase =
        qkvb + (size_t)(b * T_SEQ) * (3 * D_MODEL) + D_MODEL + h * DK;
    const unsigned short* vbase =
        vt + (size_t)(b * N_HEADS + h) * DK * T_SEQ;   // 16 tiles * 8192

    // K source-side swizzle (tile-invariant pieces)
    const int krl  = wave * 32 + (lane >> 3);
    const int kcol = ((lane & 7) ^ (lane >> 3)) * 8;

    // prologue: issue tile 0 K loads into buffer 0
#pragma unroll
    for (int i = 0; i < 4; ++i) {
        const int rk = krl + i * 8;
        __builtin_amdgcn_global_load_lds(
            (const __attribute__((address_space(1))) unsigned int*)
                (kbase + (size_t)rk * (3 * D_MODEL) + kcol),
            (__attribute__((address_space(3))) unsigned int*)
                (&Ksw[0][(wave * 4 + i) * 512]),
            16, 0, 0);
    }

    const int NT = T_SEQ / 128;
    for (int tile = 0; tile < NT; ++tile) {
        __syncthreads();   // drains this tile's K loads (issued one iter ago)

        if (tile + 1 < NT) {
            const int c0n = (tile + 1) * 128;
            const int nb  = (tile + 1) & 1;
#pragma unroll
            for (int i = 0; i < 4; ++i) {
                const int rk = krl + i * 8;
                __builtin_amdgcn_global_load_lds(
                    (const __attribute__((address_space(1))) unsigned int*)
                        (kbase + (size_t)(c0n + rk) * (3 * D_MODEL) + kcol),
                    (__attribute__((address_space(3))) unsigned int*)
                        (&Ksw[nb][(wave * 4 + i) * 512]),
                    16, 0, 0);
            }
        }

        const int cb = tile & 1;
        const unsigned short* vtile = vbase + (size_t)tile * (16 * 64 * 8);
        const unsigned short* vlane = vtile + quad * 512 + l15 * 8;
#pragma unroll
        for (int half = 0; half < 2; ++half) {
            f32x4 S[2][4];
#pragma unroll
            for (int qs = 0; qs < 2; ++qs)
#pragma unroll
                for (int nf = 0; nf < 4; ++nf) S[qs][nf] = (f32x4){0.f, 0.f, 0.f, 0.f};

            __builtin_amdgcn_s_setprio(1);
#pragma unroll
            for (int ks = 0; ks < 2; ++ks) {
                const int ch = ks * 4 + quad;
#pragma unroll
                for (int nf = 0; nf < 4; ++nf) {
                    const int row = half * 64 + nf * 16 + l15;   // kv
                    const bf16x8 kf =
                        *(const bf16x8*)&Ksw[cb][row * 64 + ((ch ^ swz) * 8)];
                    S[0][nf] = __builtin_amdgcn_mfma_f32_16x16x32_bf16(
                        kf, qa[0][ks], S[0][nf], 0, 0, 0);
                    S[1][nf] = __builtin_amdgcn_mfma_f32_16x16x32_bf16(
                        kf, qa[1][ks], S[1][nf], 0, 0, 0);
                }
            }
            __builtin_amdgcn_s_setprio(0);

#pragma unroll
            for (int gl = 0; gl < 2; ++gl) {
                bf16x8 pf[2];
#pragma unroll
                for (int qs = 0; qs < 2; ++qs) {
                    union { uint4 u; bf16x8 v; } cv;
                    const f32x4 s0 = S[qs][2 * gl];
                    const f32x4 s1 = S[qs][2 * gl + 1];
                    cv.u.x = pack_bf16x2(__builtin_amdgcn_exp2f(s0[0]),
                                         __builtin_amdgcn_exp2f(s0[1]));
                    cv.u.y = pack_bf16x2(__builtin_amdgcn_exp2f(s0[2]),
                                         __builtin_amdgcn_exp2f(s0[3]));
                    cv.u.z = pack_bf16x2(__builtin_amdgcn_exp2f(s1[0]),
                                         __builtin_amdgcn_exp2f(s1[1]));
                    cv.u.w = pack_bf16x2(__builtin_amdgcn_exp2f(s1[2]),
                                         __builtin_amdgcn_exp2f(s1[3]));
                    pf[qs] = cv.v;
                }
                const int g = half * 2 + gl;
                // V fragments direct from global (fragment-major layout):
                // 16 lanes of a quad-group read 256B contiguous.
                const unsigned short* vptr = vlane + (size_t)g * 2048;
                __builtin_amdgcn_s_setprio(1);
#pragma unroll
                for (int nd = 0; nd < 4; ++nd) {
                    const bf16x8 vb = *(const bf16x8*)(vptr + nd * 128);
                    O[0][nd] = __builtin_amdgcn_mfma_f32_16x16x32_bf16(
                        pf[0], vb, O[0][nd], 0, 0, 0);
                    O[1][nd] = __builtin_amdgcn_mfma_f32_16x16x32_bf16(
                        pf[1], vb, O[1][nd], 0, 0, 0);
                }
                Lacc[0] = __builtin_amdgcn_mfma_f32_16x16x32_bf16(
                    pf[0], ones8, Lacc[0], 0, 0, 0);
                Lacc[1] = __builtin_amdgcn_mfma_f32_16x16x32_bf16(
                    pf[1], ones8, Lacc[1], 0, 0, 0);
                __builtin_amdgcn_s_setprio(0);
            }
        }
    }

    // epilogue: single bf16 plane
#pragma unroll
    for (int qs = 0; qs < 2; ++qs)
#pragma unroll
        for (int r = 0; r < 4; ++r) {
            const float invl = 1.0f / Lacc[qs][r];
            const size_t rowbase =
                ((size_t)(b * T_SEQ) + q0 + wave * 32 + qs * 16 + quad * 4 + r)
                * D_MODEL + h * DK + l15;
#pragma unroll
            for (int nd = 0; nd < 4; ++nd)
                ob[rowbase + nd * 16] = f32_to_bf16(O[qs][nd][r] * invl);
        }
}

// ---------------------------------------------------------------------------
extern "C" void kernel_launch(void* const* d_in, const int* in_sizes, int n_in,
                              void* d_out, int out_size, void* d_ws, size_t ws_size,
                              hipStream_t stream)
{
    const float* x      = (const float*)d_in[0];
    const float* W_qkv  = (const float*)d_in[1];
    const float* W_proj = (const float*)d_in[2];
    float* out = (float*)d_out;

    unsigned short* xb   = (unsigned short*)d_ws;
    unsigned short* wqb  = xb + XN;          // fragment-major
    unsigned short* wpb  = wqb + WQ;         // fragment-major
    unsigned short* qkvb = wpb + WP;
    unsigned short* vtb  = qkvb + (size_t)M_ROWS * 3 * D_MODEL;
    unsigned short* ab   = xb;   // overlay (x plane dead after QKV GEMM)

    dim3 blk(256);
    cast_all<<<1024, blk, 0, stream>>>(x, W_qkv, W_proj, xb, wqb, wpb);

    // QKV GEMM (+fused vt build): 24 N-tiles x 64 M-tiles = 1536 blocks
    gemm_bf16_nt<unsigned short, true>
        <<<dim3((3 * D_MODEL / 128) * (M_ROWS / 128)), blk, 0, stream>>>(
        xb, wqb, qkvb, vtb, M_ROWS, 3 * D_MODEL, D_MODEL);

    attn_mfma<<<dim3(T_SEQ / 128, N_HEADS, B_SZ), blk, 0, stream>>>(
        qkvb, vtb, ab);

    // proj GEMM: 8 N-tiles x 64 M-tiles -> 512 blocks
    gemm_bf16_nt<float, false>
        <<<dim3((D_MODEL / 128) * (M_ROWS / 128)), blk, 0, stream>>>(
        ab, wpb, out, nullptr, M_ROWS, D_MODEL, D_MODEL);
}

// Round 15
// 269.399 us; speedup vs baseline: 1.0129x; 1.0129x over previous
//
#include <hip/hip_runtime.h>
#include <hip/hip_bf16.h>

#define D_MODEL 1024
#define N_HEADS 16
#define DK 64
#define B_SZ 4
#define T_SEQ 2048
#define M_ROWS (B_SZ * T_SEQ)   // 8192
#define QK_SCALE_LOG2 0.18033688f   // 0.125 * log2(e), folded into W_qkv Q-rows

#define XN ((size_t)M_ROWS * D_MODEL)        // 8388608
#define WQ ((size_t)3 * D_MODEL * D_MODEL)   // 3145728
#define WP ((size_t)D_MODEL * D_MODEL)       // 1048576

typedef short bf16x8 __attribute__((ext_vector_type(8)));
typedef float f32x4  __attribute__((ext_vector_type(4)));

__device__ inline unsigned short f32_to_bf16(float f) {
    union { float f; unsigned int u; } v; v.f = f;
    unsigned int r = v.u + 0x7fff + ((v.u >> 16) & 1);   // RNE
    return (unsigned short)(r >> 16);
}
__device__ inline unsigned int pack_bf16x2(float a, float b) {
    __hip_bfloat162 t = __float22bfloat162_rn(make_float2(a, b));
    union { __hip_bfloat162 v; unsigned int u; } c; c.v = t;
    return c.u;   // low 16 = a
}

// ---------------------------------------------------------------------------
// Single cast kernel for all three fp32->bf16 planes (linear layouts — R23's
// fragment-major W + B-direct regressed 25us: no LDS amortization of B).
// W_qkv's first D*D elements (Q rows) get the QK scale folded in.
// ---------------------------------------------------------------------------
__global__ __launch_bounds__(256) void cast_all(
    const float* __restrict__ x, const float* __restrict__ W_qkv,
    const float* __restrict__ W_proj,
    unsigned short* __restrict__ xb, unsigned short* __restrict__ wqb,
    unsigned short* __restrict__ wpb)
{
    const size_t total = (XN + WQ + WP) / 4;
    for (size_t i4 = blockIdx.x * 256 + threadIdx.x; i4 < total;
         i4 += gridDim.x * 256) {
        const size_t i = i4 * 4;
        const float* src; unsigned short* dst; float sc = 1.0f; size_t off;
        if (i < XN) {
            src = x; dst = xb; off = i;
        } else if (i < XN + WQ) {
            off = i - XN; src = W_qkv; dst = wqb;
            if (off < (size_t)D_MODEL * D_MODEL) sc = QK_SCALE_LOG2;
        } else {
            off = i - XN - WQ; src = W_proj; dst = wpb;
        }
        float4 v = *(const float4*)(src + off);
        ushort4 h;
        h.x = f32_to_bf16(v.x * sc); h.y = f32_to_bf16(v.y * sc);
        h.z = f32_to_bf16(v.z * sc); h.w = f32_to_bf16(v.w * sc);
        *(ushort4*)(dst + off) = h;
    }
}

// ---------------------------------------------------------------------------
// bf16 NT GEMM. R24: one-barrier dbuf K-loop (R22, proven +24us) at BK=32 —
// LDS 64->32KB so 4 blocks/CU (R22's 2 blocks/CU starved TLP: MFMA floor
// 24us vs ~75 actual on QKV). Swizzle widened for 64B row stride:
//   f(row) = (row&3)^((row>>2)&3); source cg = (lane&3)^((lane>>2)&3)^quad;
//   read slot = quad^f(l15) — element-traced, worst 2-way (free, m136).
// FUSE_VT (R20): V-output tiles write attn-ready fragment-major vt directly.
// ---------------------------------------------------------------------------
template <typename OutT, bool FUSE_VT>
__global__ __launch_bounds__(256, 4) void gemm_bf16_nt(
    const unsigned short* __restrict__ A, const unsigned short* __restrict__ B,
    OutT* __restrict__ C, unsigned short* __restrict__ vt,
    int M, int N, int K)
{
    __shared__ __align__(16) unsigned short sA[2][128 * 32];
    __shared__ __align__(16) unsigned short sB[2][128 * 32];

    const int t    = threadIdx.x;
    const int wave = t >> 6;
    const int lane = t & 63;
    const int l15  = lane & 15;
    const int quad = lane >> 4;

    // T1 bijective XCD swizzle (gridDim.x % 8 == 0), N fastest (R20 mapping).
    const int cpx = gridDim.x >> 3;
    const int wg  = (blockIdx.x & 7) * cpx + (blockIdx.x >> 3);
    const int nbx = N >> 7;
    const int n0  = (wg % nbx) * 128;
    const int m0  = (wg / nbx) * 128;

    // staging: waves 0-1 -> A rows, waves 2-3 -> B rows; 4 gload_lds/thread.
    // Each load i covers rows row0 + i*16 + (lane>>2), src chunk cg (16B).
    const unsigned short* gplane = (wave < 2) ? A : B;
    unsigned short* lplane = (wave < 2) ? sA[0] : sB[0];
    const int row0 = ((wave < 2) ? m0 : n0) + (wave & 1) * 64;
    const int loff = (wave & 1) * 2048;              // elements within buffer
    const int rsub = lane >> 2;                      // 0..15
    const int cg   = (lane & 3) ^ ((lane >> 2) & 3) ^ quad;
    const unsigned short* gbase =
        gplane + (size_t)(row0 + rsub) * K + cg * 8;

    f32x4 acc[4][4];
#pragma unroll
    for (int i = 0; i < 4; ++i)
#pragma unroll
        for (int j = 0; j < 4; ++j) acc[i][j] = (f32x4){0.f, 0.f, 0.f, 0.f};

    const int wr = (wave >> 1) * 64;
    const int wc = (wave & 1) * 64;
    const int fr = (l15 & 3) ^ ((l15 >> 2) & 3);     // f(row) on read side
    const int co = (quad ^ fr) * 8;                  // stored chunk * 8

    const int nk = K >> 5;
    // prologue: stage K-tile 0 into buffer 0
#pragma unroll
    for (int i = 0; i < 4; ++i) {
        __builtin_amdgcn_global_load_lds(
            (const __attribute__((address_space(1))) unsigned int*)
                (gbase + (size_t)(i * 16) * K),
            (__attribute__((address_space(3))) unsigned int*)
                (lplane + loff + i * 512),
            16, 0, 0);
    }

    for (int kt = 0; kt < nk; ++kt) {
        __syncthreads();   // drains this tile's loads (issued one iter ago)

        if (kt + 1 < nk) {
            const int k0n = (kt + 1) << 5;
            const int nb  = (kt + 1) & 1;
#pragma unroll
            for (int i = 0; i < 4; ++i) {
                __builtin_amdgcn_global_load_lds(
                    (const __attribute__((address_space(1))) unsigned int*)
                        (gbase + k0n + (size_t)(i * 16) * K),
                    (__attribute__((address_space(3))) unsigned int*)
                        (lplane + nb * 4096 + loff + i * 512),
                    16, 0, 0);
            }
        }

        const int cb = kt & 1;
        bf16x8 a[4], b[4];
#pragma unroll
        for (int f = 0; f < 4; ++f) {
            a[f] = *(const bf16x8*)&sA[cb][(wr + f * 16 + l15) * 32 + co];
            b[f] = *(const bf16x8*)&sB[cb][(wc + f * 16 + l15) * 32 + co];
        }
        __builtin_amdgcn_s_setprio(1);
#pragma unroll
        for (int mi = 0; mi < 4; ++mi)
#pragma unroll
            for (int ni = 0; ni < 4; ++ni)
                acc[mi][ni] = __builtin_amdgcn_mfma_f32_16x16x32_bf16(
                    a[mi], b[ni], acc[mi][ni], 0, 0, 0);
        __builtin_amdgcn_s_setprio(0);
    }

    if constexpr (FUSE_VT) {
        if (n0 >= 2 * D_MODEL) {
            // V tile: write attn-ready vt fragments only (no qkvb write).
            const int bb   = m0 >> 11;            // batch (2048 rows each)
            const int tile = (m0 & 2047) >> 7;    // kv tile within batch
            const int hA   = (n0 + wc - 2 * D_MODEL) >> 6;   // head of this wave
            unsigned short* vtile =
                vt + ((size_t)((bb * N_HEADS + hA) * (T_SEQ / 128) + tile))
                     * (16 * 64 * 8);
            const int chi = (wr >> 6) * 8;
#pragma unroll
            for (int cc = 0; cc < 2; ++cc) {
                const int c   = chi + cc * 4 + quad;
                const int mi0 = 2 * cc;
#pragma unroll
                for (int ni = 0; ni < 4; ++ni) {
                    const int d = ni * 16 + l15;
                    uint4 p;
                    p.x = pack_bf16x2(acc[mi0][ni][0],     acc[mi0][ni][1]);
                    p.y = pack_bf16x2(acc[mi0][ni][2],     acc[mi0][ni][3]);
                    p.z = pack_bf16x2(acc[mi0 + 1][ni][0], acc[mi0 + 1][ni][1]);
                    p.w = pack_bf16x2(acc[mi0 + 1][ni][2], acc[mi0 + 1][ni][3]);
                    *(uint4*)(vtile + (c * 64 + d) * 8) = p;
                }
            }
            return;
        }
    }

#pragma unroll
    for (int mi = 0; mi < 4; ++mi)
#pragma unroll
        for (int r = 0; r < 4; ++r) {
            OutT* crow =
                C + (size_t)(m0 + wr + mi * 16 + quad * 4 + r) * N + n0 + wc + l15;
#pragma unroll
            for (int ni = 0; ni < 4; ++ni) {
                if constexpr (sizeof(OutT) == 2)
                    crow[ni * 16] = (OutT)f32_to_bf16(acc[mi][ni][r]);
                else
                    crow[ni * 16] = (OutT)acc[mi][ni][r];
            }
        }
}

// ---------------------------------------------------------------------------
// MFMA flash attention. R16 structure (best measured) — setprio around MFMA
// clusters, V at point of use from fragment-major global layout, K double-
// buffered via global_load_lds. R14/R15/R17/R18 all regressed: no extra V
// register buffering, no bigger Q tile.
// ---------------------------------------------------------------------------
__global__ __launch_bounds__(256, 4) void attn_mfma(
    const unsigned short* __restrict__ qkvb,   // [B,T,3D] bf16 (Q pre-scaled)
    const unsigned short* __restrict__ vt,     // [bh][tile][16][64][8] bf16
    unsigned short* __restrict__ ob)           // [B,T,D] bf16
{
    __shared__ __align__(16) unsigned short Ksw[2][128 * 64];  // [kv][dk] swizzled

    const int t    = threadIdx.x;
    const int wave = t >> 6;
    const int lane = t & 63;
    const int l15  = t & 15;
    const int quad = lane >> 4;
    const int swz  = l15 & 7;

    const int b  = blockIdx.z;
    const int h  = blockIdx.y;
    const int q0 = blockIdx.x * 128;

    // Q fragments (loop-invariant): 2 q-subtiles x 2 dk-chunks
    bf16x8 qa[2][2];
#pragma unroll
    for (int qs = 0; qs < 2; ++qs) {
        const unsigned short* qrow =
            qkvb + ((size_t)(b * T_SEQ) + q0 + wave * 32 + qs * 16 + l15)
                   * (3 * D_MODEL) + h * DK;
        qa[qs][0] = *(const bf16x8*)(qrow + quad * 8);
        qa[qs][1] = *(const bf16x8*)(qrow + 32 + quad * 8);
    }

    f32x4 O[2][4], Lacc[2];
#pragma unroll
    for (int qs = 0; qs < 2; ++qs) {
        Lacc[qs] = (f32x4){0.f, 0.f, 0.f, 0.f};
#pragma unroll
        for (int nd = 0; nd < 4; ++nd) O[qs][nd] = (f32x4){0.f, 0.f, 0.f, 0.f};
    }

    const short one_bf = (short)0x3F80;
    const bf16x8 ones8 = {one_bf, one_bf, one_bf, one_bf,
                          one_bf, one_bf, one_bf, one_bf};

    const unsigned short* kbase =
        qkvb + (size_t)(b * T_SEQ) * (3 * D_MODEL) + D_MODEL + h * DK;
    const unsigned short* vbase =
        vt + (size_t)(b * N_HEADS + h) * DK * T_SEQ;   // 16 tiles * 8192

    // K source-side swizzle (tile-invariant pieces)
    const int krl  = wave * 32 + (lane >> 3);
    const int kcol = ((lane & 7) ^ (lane >> 3)) * 8;

    // prologue: issue tile 0 K loads into buffer 0
#pragma unroll
    for (int i = 0; i < 4; ++i) {
        const int rk = krl + i * 8;
        __builtin_amdgcn_global_load_lds(
            (const __attribute__((address_space(1))) unsigned int*)
                (kbase + (size_t)rk * (3 * D_MODEL) + kcol),
            (__attribute__((address_space(3))) unsigned int*)
                (&Ksw[0][(wave * 4 + i) * 512]),
            16, 0, 0);
    }

    const int NT = T_SEQ / 128;
    for (int tile = 0; tile < NT; ++tile) {
        __syncthreads();   // drains this tile's K loads (issued one iter ago)

        if (tile + 1 < NT) {
            const int c0n = (tile + 1) * 128;
            const int nb  = (tile + 1) & 1;
#pragma unroll
            for (int i = 0; i < 4; ++i) {
                const int rk = krl + i * 8;
                __builtin_amdgcn_global_load_lds(
                    (const __attribute__((address_space(1))) unsigned int*)
                        (kbase + (size_t)(c0n + rk) * (3 * D_MODEL) + kcol),
                    (__attribute__((address_space(3))) unsigned int*)
                        (&Ksw[nb][(wave * 4 + i) * 512]),
                    16, 0, 0);
            }
        }

        const int cb = tile & 1;
        const unsigned short* vtile = vbase + (size_t)tile * (16 * 64 * 8);
        const unsigned short* vlane = vtile + quad * 512 + l15 * 8;
#pragma unroll
        for (int half = 0; half < 2; ++half) {
            f32x4 S[2][4];
#pragma unroll
            for (int qs = 0; qs < 2; ++qs)
#pragma unroll
                for (int nf = 0; nf < 4; ++nf) S[qs][nf] = (f32x4){0.f, 0.f, 0.f, 0.f};

            __builtin_amdgcn_s_setprio(1);
#pragma unroll
            for (int ks = 0; ks < 2; ++ks) {
                const int ch = ks * 4 + quad;
#pragma unroll
                for (int nf = 0; nf < 4; ++nf) {
                    const int row = half * 64 + nf * 16 + l15;   // kv
                    const bf16x8 kf =
                        *(const bf16x8*)&Ksw[cb][row * 64 + ((ch ^ swz) * 8)];
                    S[0][nf] = __builtin_amdgcn_mfma_f32_16x16x32_bf16(
                        kf, qa[0][ks], S[0][nf], 0, 0, 0);
                    S[1][nf] = __builtin_amdgcn_mfma_f32_16x16x32_bf16(
                        kf, qa[1][ks], S[1][nf], 0, 0, 0);
                }
            }
            __builtin_amdgcn_s_setprio(0);

#pragma unroll
            for (int gl = 0; gl < 2; ++gl) {
                bf16x8 pf[2];
#pragma unroll
                for (int qs = 0; qs < 2; ++qs) {
                    union { uint4 u; bf16x8 v; } cv;
                    const f32x4 s0 = S[qs][2 * gl];
                    const f32x4 s1 = S[qs][2 * gl + 1];
                    cv.u.x = pack_bf16x2(__builtin_amdgcn_exp2f(s0[0]),
                                         __builtin_amdgcn_exp2f(s0[1]));
                    cv.u.y = pack_bf16x2(__builtin_amdgcn_exp2f(s0[2]),
                                         __builtin_amdgcn_exp2f(s0[3]));
                    cv.u.z = pack_bf16x2(__builtin_amdgcn_exp2f(s1[0]),
                                         __builtin_amdgcn_exp2f(s1[1]));
                    cv.u.w = pack_bf16x2(__builtin_amdgcn_exp2f(s1[2]),
                                         __builtin_amdgcn_exp2f(s1[3]));
                    pf[qs] = cv.v;
                }
                const int g = half * 2 + gl;
                // V fragments direct from global (fragment-major layout):
                // 16 lanes of a quad-group read 256B contiguous.
                const unsigned short* vptr = vlane + (size_t)g * 2048;
                __builtin_amdgcn_s_setprio(1);
#pragma unroll
                for (int nd = 0; nd < 4; ++nd) {
                    const bf16x8 vb = *(const bf16x8*)(vptr + nd * 128);
                    O[0][nd] = __builtin_amdgcn_mfma_f32_16x16x32_bf16(
                        pf[0], vb, O[0][nd], 0, 0, 0);
                    O[1][nd] = __builtin_amdgcn_mfma_f32_16x16x32_bf16(
                        pf[1], vb, O[1][nd], 0, 0, 0);
                }
                Lacc[0] = __builtin_amdgcn_mfma_f32_16x16x32_bf16(
                    pf[0], ones8, Lacc[0], 0, 0, 0);
                Lacc[1] = __builtin_amdgcn_mfma_f32_16x16x32_bf16(
                    pf[1], ones8, Lacc[1], 0, 0, 0);
                __builtin_amdgcn_s_setprio(0);
            }
        }
    }

    // epilogue: single bf16 plane
#pragma unroll
    for (int qs = 0; qs < 2; ++qs)
#pragma unroll
        for (int r = 0; r < 4; ++r) {
            const float invl = 1.0f / Lacc[qs][r];
            const size_t rowbase =
                ((size_t)(b * T_SEQ) + q0 + wave * 32 + qs * 16 + quad * 4 + r)
                * D_MODEL + h * DK + l15;
#pragma unroll
            for (int nd = 0; nd < 4; ++nd)
                ob[rowbase + nd * 16] = f32_to_bf16(O[qs][nd][r] * invl);
        }
}

// ---------------------------------------------------------------------------
extern "C" void kernel_launch(void* const* d_in, const int* in_sizes, int n_in,
                              void* d_out, int out_size, void* d_ws, size_t ws_size,
                              hipStream_t stream)
{
    const float* x      = (const float*)d_in[0];
    const float* W_qkv  = (const float*)d_in[1];
    const float* W_proj = (const float*)d_in[2];
    float* out = (float*)d_out;

    unsigned short* xb   = (unsigned short*)d_ws;
    unsigned short* wqb  = xb + XN;
    unsigned short* wpb  = wqb + WQ;
    unsigned short* qkvb = wpb + WP;
    unsigned short* vtb  = qkvb + (size_t)M_ROWS * 3 * D_MODEL;
    unsigned short* ab   = xb;   // overlay (x plane dead after QKV GEMM)

    dim3 blk(256);
    cast_all<<<1024, blk, 0, stream>>>(x, W_qkv, W_proj, xb, wqb, wpb);

    // QKV GEMM (+fused vt build): 24 N-tiles x 64 M-tiles = 1536 blocks
    gemm_bf16_nt<unsigned short, true>
        <<<dim3((3 * D_MODEL / 128) * (M_ROWS / 128)), blk, 0, stream>>>(
        xb, wqb, qkvb, vtb, M_ROWS, 3 * D_MODEL, D_MODEL);

    attn_mfma<<<dim3(T_SEQ / 128, N_HEADS, B_SZ), blk, 0, stream>>>(
        qkvb, vtb, ab);

    // proj GEMM: 8 N-tiles x 64 M-tiles -> 512 blocks
    gemm_bf16_nt<float, false>
        <<<dim3((D_MODEL / 128) * (M_ROWS / 128)), blk, 0, stream>>>(
        ab, wpb, out, nullptr, M_ROWS, D_MODEL, D_MODEL);
}